// Round 9
// baseline (380.709 us; speedup 1.0000x reference)
//
#include <hip/hip_runtime.h>

#define NPTS 8192
#define HDIM 64
#define KNN 16
#define LOG2E 1.4426950408889634f

typedef __attribute__((ext_vector_type(8))) short bf8_t;   // 8 bf16
typedef __attribute__((ext_vector_type(4))) float f4_t;    // MFMA C/D
#define MFMA16(a, b, c) __builtin_amdgcn_mfma_f32_16x16x32_bf16(a, b, c, 0, 0, 0)

__device__ __forceinline__ float fast_exp(float x) {
    float y = x * LOG2E;
    float r;
    asm volatile("v_exp_f32 %0, %1\n\ts_nop 1" : "=v"(r) : "v"(y));
    return r;
}
__device__ __forceinline__ unsigned short f2b(float x) {   // f32 -> bf16 RNE
    unsigned v = __float_as_uint(x);
    return (unsigned short)((v + 0x7FFFu + ((v >> 16) & 1u)) >> 16);
}

// ws layout: qw 0..4MB, kw 4..8MB, vw 8..12MB, frag 12MB..+24KB, knnIdx +32KB..+1MB
#define OFF_QW   0u
#define OFF_KW   (4u << 20)
#define OFF_VW   (8u << 20)
#define OFF_FRAG (12u << 20)
#define OFF_KNN  ((12u << 20) + 32768u)     // ws >= 14.8 MB (established R12)

// ---------------------------------------------------------------------------
// prefrag: pack Wp2/Wt1/Wt2 into MFMA B-frag order (proven R11-R15).
// ---------------------------------------------------------------------------
__global__ void prefrag_kernel(const float* __restrict__ Wp2,
                               const float* __restrict__ Wt1,
                               const float* __restrict__ Wt2,
                               unsigned short* __restrict__ dst)
{
    int i = blockIdx.x * 256 + threadIdx.x;
    if (i >= 3 * 4096) return;
    int st = i >> 12, e = i & 4095;
    const float* W = (st == 0) ? Wp2 : (st == 1) ? Wt1 : Wt2;
    int k = e >> 6, n = e & 63;
    int s = k >> 5, quad = (k >> 3) & 3, j = k & 7;
    int t = n >> 4, l = quad * 16 + (n & 15);
    dst[st * 4096 + (s * 4 + t) * 512 + l * 8 + j] = f2b(W[e]);
}

// ---------------------------------------------------------------------------
// proj v2: LDS-staged weights (proven R14+). Inner math f32, bit-identical.
// ---------------------------------------------------------------------------
__global__ __launch_bounds__(1024) void proj_kernel(
    const float* __restrict__ feat,
    const float* __restrict__ Wk, const float* __restrict__ bk,
    const float* __restrict__ Wq, const float* __restrict__ Wks,
    const float* __restrict__ Wv,
    float* __restrict__ qw, float* __restrict__ kw, float* __restrict__ vw)
{
    __shared__ __align__(16) float4 sW[4][1024];   // Wk, Wq, Wks, Wv (64 KB)
    int tid = threadIdx.x;
    sW[0][tid] = ((const float4*)Wk)[tid];
    sW[1][tid] = ((const float4*)Wq)[tid];
    sW[2][tid] = ((const float4*)Wks)[tid];
    sW[3][tid] = ((const float4*)Wv)[tid];
    __syncthreads();
    const float* sWk  = (const float*)sW[0];
    const float* sWq  = (const float*)sW[1];
    const float* sWks = (const float*)sW[2];
    const float* sWv  = (const float*)sW[3];

    int w = tid >> 6, lane = tid & 63;
    int p = blockIdx.x * 16 + w;
    float f = feat[(size_t)p * HDIM + lane];
    float x = bk[lane];
    #pragma unroll 8
    for (int c = 0; c < 64; ++c) x += __shfl(f, c) * sWk[c * 64 + lane];
    float q = 0.f, k = 0.f, v = 0.f;
    #pragma unroll 8
    for (int c = 0; c < 64; ++c) {
        float xc = __shfl(x, c);
        q += xc * sWq[c * 64 + lane];
        k += xc * sWks[c * 64 + lane];
        v += xc * sWv[c * 64 + lane];
    }
    qw[(size_t)p * HDIM + lane] = q;
    kw[(size_t)p * HDIM + lane] = k;
    vw[(size_t)p * HDIM + lane] = v;
}

// ---------------------------------------------------------------------------
// knn v10: DISTANCE-ONLY scan + threshold recovery.
// R22 post-mortem: four structures (R15 bubble / R16 cndmask / R18 tau /
// R22 query-split) all converge to ~300K busy-cy/SIMD @ ~63% VALUBusy —
// the invariant cost is the (d,index) insert machinery (~20+ VALU/pair,
// near-unconditional). The downstream attention is PERMUTATION-INVARIANT
// over the k axis (softmax+sum), so the scan only needs the top-16 SET.
// New: (1) scan keeps 4 smallest DISTANCES per lane via a pure min/max
// network — 7 VALU/pair, zero cmp/cndmask/branch; (2) knockout over the
// 256-value union yields thr = 16th-smallest-of-union >= true global 16th
// (union is a subset; duplicate multi-removal only raises thr — still a
// valid upper bound); (3) recovery rescan collects all d <= thr (~16
// hits/wave, bit-identical d expression) into the proven (eh,ei) repair
// list; (d, lower-index) knockout emits exactly the reference top-k set.
// Per-lane overflow (cnt>16, pathological clustering) -> proven full exact
// repair fallback. All per-thread arrays indexed by compile-time constants
// (rule #20).
// ---------------------------------------------------------------------------
__global__ __launch_bounds__(256) void knn2_kernel(
    const float* __restrict__ xyzp, int* __restrict__ knnIdx)
{
    int w = threadIdx.x >> 6, lane = threadIdx.x & 63;
    int wid = blockIdx.x * 4 + w;        // wave id 0..8191
    int pbase = wid * 2;                 // 2 consecutive points, same batch
    int b = pbase >> 13;
    int nbase = pbase & (NPTS - 1);
    const float4* xb4 = (const float4*)xyzp + (size_t)b * NPTS;

    float qx[2], qy[2], qz[2], qs[2];
    #pragma unroll
    for (int qi = 0; qi < 2; ++qi) {
        float4 s = xb4[nbase + qi];
        qx[qi] = s.x; qy[qi] = s.y; qz[qi] = s.z;
        qs[qi] = s.x * s.x + s.y * s.y + s.z * s.z;
    }

    float dh[2][4];
    #pragma unroll
    for (int qi = 0; qi < 2; ++qi)
        #pragma unroll
        for (int j = 0; j < 4; ++j) dh[qi][j] = 3.4e38f;

    // ---- pass 1: distance-only scan (pure VALU, no branches) ----
    #pragma unroll 1
    for (int t = 0; t < NPTS / 256; ++t) {          // 32 iters x 256 cands
        float4 c[4];
        #pragma unroll
        for (int u = 0; u < 4; ++u)
            c[u] = xb4[(t * 4 + u) * 64 + lane];
        #pragma unroll
        for (int u = 0; u < 4; ++u) {
            float cs = c[u].x * c[u].x + c[u].y * c[u].y + c[u].z * c[u].z;
            #pragma unroll
            for (int qi = 0; qi < 2; ++qi) {
                float d = qs[qi] + cs
                        - 2.0f * (qx[qi] * c[u].x + qy[qi] * c[u].y + qz[qi] * c[u].z);
                // sorted keep-4-smallest, distances only: 7 min/max
                float b1 = fmaxf(dh[qi][0], d);  dh[qi][0] = fminf(dh[qi][0], d);
                float b2 = fmaxf(dh[qi][1], b1); dh[qi][1] = fminf(dh[qi][1], b1);
                float b3 = fmaxf(dh[qi][2], b2); dh[qi][2] = fminf(dh[qi][2], b2);
                dh[qi][3] = fminf(dh[qi][3], b3);
            }
        }
    }

    // ---- per qi: threshold extraction + index recovery ----
    #pragma unroll
    for (int qi = 0; qi < 2; ++qi) {
        // knockout over the 256-value union: thr = 16th extracted minimum
        // (>= true global 16th-best; see header comment)
        float thr = 3.4e38f;
        #pragma unroll 1
        for (int r = 0; r < KNN; ++r) {
            float dmin = dh[qi][0];
            #pragma unroll
            for (int s = 1; s < 64; s <<= 1)
                dmin = fminf(dmin, __shfl_xor(dmin, s));
            if (r == KNN - 1) thr = dmin;
            if (dh[qi][0] == dmin) {
                dh[qi][0] = dh[qi][1]; dh[qi][1] = dh[qi][2];
                dh[qi][2] = dh[qi][3]; dh[qi][3] = 3.4e38f;
            }
        }

        // recovery rescan: collect all candidates with d <= thr
        float eh[16]; int ei[16];
        #pragma unroll
        for (int j = 0; j < 16; ++j) { eh[j] = 3.4e38f; ei[j] = 0x7fffffff; }
        int cnt = 0;
        #pragma unroll 1
        for (int t2 = 0; t2 < NPTS / 64; ++t2) {
            int m = t2 * 64 + lane;
            float4 c4 = xb4[m];
            float cs = c4.x * c4.x + c4.y * c4.y + c4.z * c4.z;
            float d = qs[qi] + cs
                    - 2.0f * (qx[qi] * c4.x + qy[qi] * c4.y + qz[qi] * c4.z);
            if (d <= thr) {
                ++cnt;
                if (d < eh[15]) {        // first 16 hits always insert (eh[15]=inf)
                    eh[15] = d; ei[15] = m;
                    #pragma unroll
                    for (int j = 15; j >= 1; --j)
                        if (eh[j] < eh[j - 1]) {
                            float td = eh[j]; eh[j] = eh[j - 1]; eh[j - 1] = td;
                            int ti = ei[j]; ei[j] = ei[j - 1]; ei[j - 1] = ti;
                        }
                }
            }
        }

        int mynb = 0;
        if (__any(cnt > 16)) {
            // fallback: full exact 16-deep repair (proven R13-R15 code)
            #pragma unroll
            for (int j = 0; j < 16; ++j) { eh[j] = 3.4e38f; ei[j] = 0x7fffffff; }
            for (int t2 = 0; t2 < NPTS / 64; ++t2) {
                int m = t2 * 64 + lane;
                float4 c4 = xb4[m];
                float cs = c4.x * c4.x + c4.y * c4.y + c4.z * c4.z;
                float d = qs[qi] + cs
                        - 2.0f * (qx[qi] * c4.x + qy[qi] * c4.y + qz[qi] * c4.z);
                if (d < eh[15]) {
                    eh[15] = d; ei[15] = m;
                    #pragma unroll
                    for (int j = 15; j >= 1; --j)
                        if (eh[j] < eh[j - 1]) {
                            float td = eh[j]; eh[j] = eh[j - 1]; eh[j - 1] = td;
                            int ti = ei[j]; ei[j] = ei[j - 1]; ei[j - 1] = ti;
                        }
                }
            }
        }
        // knockout extraction by (d, lower index) — exact reference tie order
        #pragma unroll 1
        for (int r = 0; r < KNN; ++r) {
            float d = eh[0]; int i = ei[0];
            #pragma unroll
            for (int s = 1; s < 64; s <<= 1) {
                float d2 = __shfl_xor(d, s); int i2 = __shfl_xor(i, s);
                if (d2 < d || (d2 == d && i2 < i)) { d = d2; i = i2; }
            }
            if (lane == r) mynb = i;
            if (ei[0] == i) {
                #pragma unroll
                for (int j = 0; j < 15; ++j) { eh[j] = eh[j + 1]; ei[j] = ei[j + 1]; }
                eh[15] = 3.4e38f; ei[15] = 0x7fffffff;
            }
        }
        mynb = min(max(mynb, 0), NPTS - 1);
        if (lane < KNN) knnIdx[(size_t)(pbase + qi) * KNN + lane] = mynb;
    }
}

// ---------------------------------------------------------------------------
// main: MFMA per-neighbor MLPs consuming knnIdx (proven verbatim R12/R14/R15).
// ---------------------------------------------------------------------------
__global__ __launch_bounds__(256) void LocalTransformer_80513456931527_kernel(
    const float* __restrict__ xyzp, const float* __restrict__ features,
    const float* __restrict__ Wp1,  const float* __restrict__ bp1,
    const float* __restrict__ bp2,  const float* __restrict__ bt1,
    const float* __restrict__ bt2,
    const float* __restrict__ Wa,   const float* __restrict__ ba,
    const float* __restrict__ qw, const float* __restrict__ kw,
    const float* __restrict__ vw,
    const unsigned short* __restrict__ fragw,
    const int* __restrict__ knnIdx,
    float* __restrict__ out)
{
    __shared__ __align__(16) float sBounce[4][16 * 68 + 4];

    int tid = threadIdx.x, w = tid >> 6, lane = tid & 63;
    int p = blockIdx.x * 4 + w;
    int b = p >> 13;
    float* bb = sBounce[w];

    int quad = lane >> 4, l15 = lane & 15;
    int mynb = knnIdx[(size_t)p * KNN + l15];
    mynb = min(max(mynb, 0), NPTS - 1);
    int nb_a = mynb;
    int nbm[4];
    #pragma unroll
    for (int r = 0; r < 4; ++r) nbm[r] = __shfl(mynb, quad * 4 + r);

    const float4 xq4 = *(const float4*)(xyzp + (size_t)p * 4);
    const float4 xn4 = *(const float4*)(xyzp + ((size_t)b * NPTS + nb_a) * 4);
    float rel0 = xq4.x - xn4.x, rel1 = xq4.y - xn4.y;
    float rel2 = xq4.z - xn4.z, rel3 = xq4.w - xn4.w;

    bf8_t pe1f[2];
    #pragma unroll
    for (int s = 0; s < 2; ++s) {
        int hb = s * 32 + quad * 8;
        float W0[8], W1[8], W2[8], W3[8], Bb[8];
        *(float4*)&W0[0] = *(const float4*)(Wp1 +       hb);
        *(float4*)&W0[4] = *(const float4*)(Wp1 +       hb + 4);
        *(float4*)&W1[0] = *(const float4*)(Wp1 +  64 + hb);
        *(float4*)&W1[4] = *(const float4*)(Wp1 +  64 + hb + 4);
        *(float4*)&W2[0] = *(const float4*)(Wp1 + 128 + hb);
        *(float4*)&W2[4] = *(const float4*)(Wp1 + 128 + hb + 4);
        *(float4*)&W3[0] = *(const float4*)(Wp1 + 192 + hb);
        *(float4*)&W3[4] = *(const float4*)(Wp1 + 192 + hb + 4);
        *(float4*)&Bb[0] = *(const float4*)(bp1 + hb);
        *(float4*)&Bb[4] = *(const float4*)(bp1 + hb + 4);
        #pragma unroll
        for (int j = 0; j < 8; ++j) {
            float a = Bb[j] + rel0 * W0[j] + rel1 * W1[j]
                            + rel2 * W2[j] + rel3 * W3[j];
            pe1f[s][j] = (short)f2b(fmaxf(a, 0.f));
        }
    }

    const bf8_t* BW = (const bf8_t*)fragw;
    f4_t pe2c[4];
    #pragma unroll
    for (int t = 0; t < 4; ++t) {
        f4_t acc = {0.f, 0.f, 0.f, 0.f};
        acc = MFMA16(pe1f[0], BW[0 * 512 + (0 * 4 + t) * 64 + lane], acc);
        acc = MFMA16(pe1f[1], BW[0 * 512 + (1 * 4 + t) * 64 + lane], acc);
        float bias = bp2[t * 16 + l15];
        #pragma unroll
        for (int r = 0; r < 4; ++r) acc[r] += bias;
        pe2c[t] = acc;
    }

    f4_t ainc[4], vpec[4];
    #pragma unroll
    for (int t = 0; t < 4; ++t) {
        float qv = qw[(size_t)p * HDIM + t * 16 + l15];
        #pragma unroll
        for (int r = 0; r < 4; ++r) {
            size_t nbo = ((size_t)b * NPTS + nbm[r]) * HDIM + t * 16 + l15;
            ainc[t][r] = qv - kw[nbo] + pe2c[t][r];
            vpec[t][r] = vw[nbo] + pe2c[t][r];
        }
    }

    #pragma unroll
    for (int t = 0; t < 4; ++t)
        #pragma unroll
        for (int r = 0; r < 4; ++r)
            bb[(quad * 4 + r) * 68 + t * 16 + l15] = ainc[t][r];
    asm volatile("s_waitcnt lgkmcnt(0)" ::: "memory");
    bf8_t af[2];
    #pragma unroll
    for (int s = 0; s < 2; ++s) {
        float tmp[8];
        *(float4*)&tmp[0] = *(const float4*)&bb[l15 * 68 + s * 32 + quad * 8];
        *(float4*)&tmp[4] = *(const float4*)&bb[l15 * 68 + s * 32 + quad * 8 + 4];
        #pragma unroll
        for (int j = 0; j < 8; ++j) af[s][j] = (short)f2b(tmp[j]);
    }

    f4_t t1c[4];
    #pragma unroll
    for (int t = 0; t < 4; ++t) {
        f4_t acc = {0.f, 0.f, 0.f, 0.f};
        acc = MFMA16(af[0], BW[1 * 512 + (0 * 4 + t) * 64 + lane], acc);
        acc = MFMA16(af[1], BW[1 * 512 + (1 * 4 + t) * 64 + lane], acc);
        float bias = bt1[t * 16 + l15];
        #pragma unroll
        for (int r = 0; r < 4; ++r) t1c[t][r] = fmaxf(acc[r] + bias, 0.f);
    }

    asm volatile("s_waitcnt lgkmcnt(0)" ::: "memory");
    #pragma unroll
    for (int t = 0; t < 4; ++t)
        #pragma unroll
        for (int r = 0; r < 4; ++r)
            bb[(quad * 4 + r) * 68 + t * 16 + l15] = t1c[t][r];
    asm volatile("s_waitcnt lgkmcnt(0)" ::: "memory");
    bf8_t tf[2];
    #pragma unroll
    for (int s = 0; s < 2; ++s) {
        float tmp[8];
        *(float4*)&tmp[0] = *(const float4*)&bb[l15 * 68 + s * 32 + quad * 8];
        *(float4*)&tmp[4] = *(const float4*)&bb[l15 * 68 + s * 32 + quad * 8 + 4];
        #pragma unroll
        for (int j = 0; j < 8; ++j) tf[s][j] = (short)f2b(tmp[j]);
    }

    f4_t lgc[4];
    #pragma unroll
    for (int t = 0; t < 4; ++t) {
        f4_t acc = {0.f, 0.f, 0.f, 0.f};
        acc = MFMA16(tf[0], BW[2 * 512 + (0 * 4 + t) * 64 + lane], acc);
        acc = MFMA16(tf[1], BW[2 * 512 + (1 * 4 + t) * 64 + lane], acc);
        float bias = bt2[t * 16 + l15];
        #pragma unroll
        for (int r = 0; r < 4; ++r) lgc[t][r] = (acc[r] + bias) * 0.125f;
    }

    float res[4];
    #pragma unroll
    for (int t = 0; t < 4; ++t) {
        float m0 = fmaxf(fmaxf(lgc[t][0], lgc[t][1]), fmaxf(lgc[t][2], lgc[t][3]));
        m0 = fmaxf(m0, __shfl_xor(m0, 16));
        m0 = fmaxf(m0, __shfl_xor(m0, 32));
        float e0 = fast_exp(lgc[t][0] - m0), e1 = fast_exp(lgc[t][1] - m0);
        float e2 = fast_exp(lgc[t][2] - m0), e3 = fast_exp(lgc[t][3] - m0);
        float sl = e0 + e1 + e2 + e3;
        float rl = e0 * vpec[t][0] + e1 * vpec[t][1]
                 + e2 * vpec[t][2] + e3 * vpec[t][3];
        sl += __shfl_xor(sl, 16); sl += __shfl_xor(sl, 32);
        rl += __shfl_xor(rl, 16); rl += __shfl_xor(rl, 32);
        res[t] = rl / sl;
    }

    float rh = (quad == 0) ? res[0] : (quad == 1) ? res[1]
             : (quad == 2) ? res[2] : res[3];
    float f = features[(size_t)p * HDIM + lane];
    float o = ba[lane];
    #pragma unroll 8
    for (int c = 0; c < 64; ++c) o += __shfl(rh, c) * Wa[c * 64 + lane];
    out[(size_t)p * HDIM + lane] = o + f;
}

// ---------------------------------------------------------------------------
extern "C" void kernel_launch(void* const* d_in, const int* in_sizes, int n_in,
                              void* d_out, int out_size, void* d_ws, size_t ws_size,
                              hipStream_t stream)
{
    (void)in_sizes; (void)n_in; (void)out_size; (void)ws_size;
    const float* xyzp     = (const float*)d_in[0];
    const float* features = (const float*)d_in[1];
    const float* Wk  = (const float*)d_in[2];
    const float* bk  = (const float*)d_in[3];
    const float* Wq  = (const float*)d_in[4];
    const float* Wks = (const float*)d_in[5];
    const float* Wv  = (const float*)d_in[6];
    const float* Wp1 = (const float*)d_in[7];
    const float* bp1 = (const float*)d_in[8];
    const float* Wp2 = (const float*)d_in[9];
    const float* bp2 = (const float*)d_in[10];
    const float* Wt1 = (const float*)d_in[11];
    const float* bt1 = (const float*)d_in[12];
    const float* Wt2 = (const float*)d_in[13];
    const float* bt2 = (const float*)d_in[14];
    const float* Wa  = (const float*)d_in[15];
    const float* ba  = (const float*)d_in[16];
    float* out = (float*)d_out;
    char* ws = (char*)d_ws;

    float* qw = (float*)(ws + OFF_QW);
    float* kw = (float*)(ws + OFF_KW);
    float* vw = (float*)(ws + OFF_VW);
    unsigned short* fragw = (unsigned short*)(ws + OFF_FRAG);
    int* knnIdx = (int*)(ws + OFF_KNN);

    prefrag_kernel<<<48, 256, 0, stream>>>(Wp2, Wt1, Wt2, fragw);
    proj_kernel<<<(2 * NPTS) / 16, 1024, 0, stream>>>(
        features, Wk, bk, Wq, Wks, Wv, qw, kw, vw);
    knn2_kernel<<<(2 * NPTS) / 8, 256, 0, stream>>>(xyzp, knnIdx);
    LocalTransformer_80513456931527_kernel<<<(2 * NPTS) / 4, 256, 0, stream>>>(
        xyzp, features, Wp1, bp1, bp2, bt1, bt2, Wa, ba,
        qw, kw, vw, fragw, knnIdx, out);
}

// Round 10
// 335.706 us; speedup vs baseline: 1.1341x; 1.1341x over previous
//
#include <hip/hip_runtime.h>

#define NPTS 8192
#define HDIM 64
#define KNN 16
#define LOG2E 1.4426950408889634f

typedef __attribute__((ext_vector_type(8))) short bf8_t;   // 8 bf16
typedef __attribute__((ext_vector_type(4))) float f4_t;    // MFMA C/D
#define MFMA16(a, b, c) __builtin_amdgcn_mfma_f32_16x16x32_bf16(a, b, c, 0, 0, 0)

__device__ __forceinline__ float fast_exp(float x) {
    float y = x * LOG2E;
    float r;
    asm volatile("v_exp_f32 %0, %1\n\ts_nop 1" : "=v"(r) : "v"(y));
    return r;
}
__device__ __forceinline__ unsigned short f2b(float x) {   // f32 -> bf16 RNE
    unsigned v = __float_as_uint(x);
    return (unsigned short)((v + 0x7FFFu + ((v >> 16) & 1u)) >> 16);
}

// ws layout: qw 0..4MB, kw 4..8MB, vw 8..12MB, frag 12MB..+24KB, knnIdx +32KB..+1MB
#define OFF_QW   0u
#define OFF_KW   (4u << 20)
#define OFF_VW   (8u << 20)
#define OFF_FRAG (12u << 20)
#define OFF_KNN  ((12u << 20) + 32768u)     // ws >= 14.8 MB (established R12)

// ---------------------------------------------------------------------------
// fused_pre: prefrag + proj + knn packed into ONE dispatch, block-interleaved.
// R23 rationale: 9 rounds established (a) knn converges to ~200-235us across
// four scan structures, VALU-issue/latency bound, NO LDS, tiny L2 traffic;
// (b) proj is pure L2-BW (~45us serial, R14-measured, ~1GB of W re-reads);
// (c) prefrag trivial. Disjoint pipes -> co-scheduling overlaps them (m114:
// MFMA/VALU/mem waves compose to max, not sum). Fusion removes proj+prefrag
// from the critical path. knn body = R8 verbatim (best knn: 207us @ 63%
// busy; the 37% stall is what proj waves fill). proj = proven pre-LDS R14
// form (global W reads, bit-identical math), 4 waves/block x 1 point/wave,
// NO LDS so knn occupancy is not LDS-coupled. Grid order: prefrag first 48
// blocks, then triples (knn, proj, proj) so resident sets are mixed from
// t=0 (all-knn residency would serialize proj to the tail).
// ---------------------------------------------------------------------------
#define KNN_BLOCKS 2048
#define PROJ_BLOCKS 4096
#define PRE_BLOCKS 48

__global__ __launch_bounds__(256) void fused_pre_kernel(
    const float* __restrict__ xyzp,
    const float* __restrict__ feat,
    const float* __restrict__ Wk, const float* __restrict__ bk,
    const float* __restrict__ Wq, const float* __restrict__ Wks,
    const float* __restrict__ Wv,
    const float* __restrict__ Wp2, const float* __restrict__ Wt1,
    const float* __restrict__ Wt2,
    float* __restrict__ qw, float* __restrict__ kw, float* __restrict__ vw,
    unsigned short* __restrict__ fragw,
    int* __restrict__ knnIdx)
{
    int bid = blockIdx.x;

    // ---------------- prefrag path (blocks 0..47), proven R11-R15 ----------
    if (bid < PRE_BLOCKS) {
        int i = bid * 256 + threadIdx.x;
        if (i >= 3 * 4096) return;
        int st = i >> 12, e = i & 4095;
        const float* W = (st == 0) ? Wp2 : (st == 1) ? Wt1 : Wt2;
        int k = e >> 6, n = e & 63;
        int s = k >> 5, quad = (k >> 3) & 3, j = k & 7;
        int t = n >> 4, l = quad * 16 + (n & 15);
        fragw[st * 4096 + (s * 4 + t) * 512 + l * 8 + j] = f2b(W[e]);
        return;
    }

    int j3 = bid - PRE_BLOCKS;
    int triple = j3 / 3, pos = j3 - triple * 3;
    int w = threadIdx.x >> 6, lane = threadIdx.x & 63;

    // ---------------- proj path (pre-LDS R14 form, bit-identical math) -----
    if (pos != 0) {
        int pb = triple * 2 + (pos - 1);          // 0..4095
        int p = pb * 4 + w;                        // 4 points per block
        float f = feat[(size_t)p * HDIM + lane];
        float x = bk[lane];
        #pragma unroll 8
        for (int c = 0; c < 64; ++c) x += __shfl(f, c) * Wk[c * 64 + lane];
        float q = 0.f, k = 0.f, v = 0.f;
        #pragma unroll 8
        for (int c = 0; c < 64; ++c) {
            float xc = __shfl(x, c);
            q += xc * Wq[c * 64 + lane];
            k += xc * Wks[c * 64 + lane];
            v += xc * Wv[c * 64 + lane];
        }
        qw[(size_t)p * HDIM + lane] = q;
        kw[(size_t)p * HDIM + lane] = k;
        vw[(size_t)p * HDIM + lane] = v;
        return;
    }

    // ---------------- knn path (R8/knn2 body VERBATIM: best knn, 207us) ----
    int wid = triple * 4 + w;            // wave id 0..8191
    int pbase = wid * 2;                 // 2 consecutive points, same batch
    int b = pbase >> 13;
    int nbase = pbase & (NPTS - 1);
    const float4* xb4 = (const float4*)xyzp + (size_t)b * NPTS;

    float qx[2], qy[2], qz[2], qs[2];
    #pragma unroll
    for (int qi = 0; qi < 2; ++qi) {
        float4 s = xb4[nbase + qi];
        qx[qi] = s.x; qy[qi] = s.y; qz[qi] = s.z;
        qs[qi] = s.x * s.x + s.y * s.y + s.z * s.z;
    }

    float dh[2][4]; int ih[2][4];
    #pragma unroll
    for (int qi = 0; qi < 2; ++qi)
        #pragma unroll
        for (int j = 0; j < 4; ++j) { dh[qi][j] = 3.4e38f; ih[qi][j] = 0x7fffffff; }

    float tau[2];
    tau[0] = 3.4e38f; tau[1] = 3.4e38f;

    #pragma unroll 1
    for (int t = 0; t < NPTS / 256; ++t) {          // 32 iters x 256 cands
        float4 c[4];
        #pragma unroll
        for (int u = 0; u < 4; ++u)
            c[u] = xb4[(t * 4 + u) * 64 + lane];
        #pragma unroll
        for (int u = 0; u < 4; ++u) {
            int m = (t * 4 + u) * 64 + lane;
            float cs = c[u].x * c[u].x + c[u].y * c[u].y + c[u].z * c[u].z;
            #pragma unroll
            for (int qi = 0; qi < 2; ++qi) {
                float d = qs[qi] + cs
                        - 2.0f * (qx[qi] * c[u].x + qy[qi] * c[u].y + qz[qi] * c[u].z);
                if (__any(d <= tau[qi])) {
                    // branchless sorted insert (strict <, ties keep lower idx)
                    bool c3 = d < dh[qi][3];
                    bool c2 = d < dh[qi][2];
                    bool c1 = d < dh[qi][1];
                    bool c0 = d < dh[qi][0];
                    dh[qi][3] = c2 ? dh[qi][2] : (c3 ? d : dh[qi][3]);
                    ih[qi][3] = c2 ? ih[qi][2] : (c3 ? m : ih[qi][3]);
                    dh[qi][2] = c1 ? dh[qi][1] : (c2 ? d : dh[qi][2]);
                    ih[qi][2] = c1 ? ih[qi][1] : (c2 ? m : ih[qi][2]);
                    dh[qi][1] = c0 ? dh[qi][0] : (c1 ? d : dh[qi][1]);
                    ih[qi][1] = c0 ? ih[qi][0] : (c1 ? m : ih[qi][1]);
                    dh[qi][0] = c0 ? d : dh[qi][0];
                    ih[qi][0] = c0 ? m : ih[qi][0];
                }
            }
        }
        if (t & 1) {
            // tau = max over 4 groups-of-16 of (min over group of dh[3]):
            // valid upper bound on final global 16th-best (proven R18)
            #pragma unroll
            for (int qi = 0; qi < 2; ++qi) {
                float t4 = dh[qi][3];
                t4 = fminf(t4, __shfl_xor(t4, 1));
                t4 = fminf(t4, __shfl_xor(t4, 2));
                t4 = fminf(t4, __shfl_xor(t4, 4));
                t4 = fminf(t4, __shfl_xor(t4, 8));
                t4 = fmaxf(t4, __shfl_xor(t4, 16));
                t4 = fmaxf(t4, __shfl_xor(t4, 32));
                tau[qi] = t4;
            }
        }
    }

    // per-qi exact top-16 extraction + full-range repair (proven R18 code,
    // qi fully unrolled: rule #20).
    #pragma unroll
    for (int qi = 0; qi < 2; ++qi) {
        int mynb = 0, head = 0;
        #pragma unroll 1
        for (int r = 0; r < KNN; ++r) {
            float d = dh[qi][0]; int i = ih[qi][0];
            #pragma unroll
            for (int s = 1; s < 64; s <<= 1) {
                float d2 = __shfl_xor(d, s); int i2 = __shfl_xor(i, s);
                if (d2 < d || (d2 == d && i2 < i)) { d = d2; i = i2; }
            }
            if (lane == r) mynb = i;
            if (ih[qi][0] == i) {
                dh[qi][0] = dh[qi][1]; ih[qi][0] = ih[qi][1];
                dh[qi][1] = dh[qi][2]; ih[qi][1] = ih[qi][2];
                dh[qi][2] = dh[qi][3]; ih[qi][2] = ih[qi][3];
                dh[qi][3] = 3.4e38f; ih[qi][3] = 0x7fffffff;
                ++head;
            }
        }
        // exact repair (proven R13-R15): ~0.7%/query
        if (__any(head >= 4)) {
            float eh[16]; int ei[16];
            #pragma unroll
            for (int j = 0; j < 16; ++j) { eh[j] = 3.4e38f; ei[j] = 0x7fffffff; }
            for (int t = 0; t < NPTS / 64; ++t) {
                int m = t * 64 + lane;
                float4 c4 = xb4[m];
                float cs = c4.x * c4.x + c4.y * c4.y + c4.z * c4.z;
                float d = qs[qi] + cs
                        - 2.0f * (qx[qi] * c4.x + qy[qi] * c4.y + qz[qi] * c4.z);
                if (d < eh[15]) {
                    eh[15] = d; ei[15] = m;
                    #pragma unroll
                    for (int j = 15; j >= 1; --j)
                        if (eh[j] < eh[j - 1]) {
                            float td = eh[j]; eh[j] = eh[j - 1]; eh[j - 1] = td;
                            int ti = ei[j]; ei[j] = ei[j - 1]; ei[j - 1] = ti;
                        }
                }
            }
            #pragma unroll 1
            for (int r = 0; r < KNN; ++r) {
                float d = eh[0]; int i = ei[0];
                #pragma unroll
                for (int s = 1; s < 64; s <<= 1) {
                    float d2 = __shfl_xor(d, s); int i2 = __shfl_xor(i, s);
                    if (d2 < d || (d2 == d && i2 < i)) { d = d2; i = i2; }
                }
                if (lane == r) mynb = i;
                if (ei[0] == i) {
                    #pragma unroll
                    for (int j = 0; j < 15; ++j) { eh[j] = eh[j + 1]; ei[j] = ei[j + 1]; }
                    eh[15] = 3.4e38f; ei[15] = 0x7fffffff;
                }
            }
        }
        mynb = min(max(mynb, 0), NPTS - 1);
        if (lane < KNN) knnIdx[(size_t)(pbase + qi) * KNN + lane] = mynb;
    }
}

// ---------------------------------------------------------------------------
// main: MFMA per-neighbor MLPs consuming knnIdx (proven verbatim R12/R14/R15).
// ---------------------------------------------------------------------------
__global__ __launch_bounds__(256) void LocalTransformer_80513456931527_kernel(
    const float* __restrict__ xyzp, const float* __restrict__ features,
    const float* __restrict__ Wp1,  const float* __restrict__ bp1,
    const float* __restrict__ bp2,  const float* __restrict__ bt1,
    const float* __restrict__ bt2,
    const float* __restrict__ Wa,   const float* __restrict__ ba,
    const float* __restrict__ qw, const float* __restrict__ kw,
    const float* __restrict__ vw,
    const unsigned short* __restrict__ fragw,
    const int* __restrict__ knnIdx,
    float* __restrict__ out)
{
    __shared__ __align__(16) float sBounce[4][16 * 68 + 4];

    int tid = threadIdx.x, w = tid >> 6, lane = tid & 63;
    int p = blockIdx.x * 4 + w;
    int b = p >> 13;
    float* bb = sBounce[w];

    int quad = lane >> 4, l15 = lane & 15;
    int mynb = knnIdx[(size_t)p * KNN + l15];
    mynb = min(max(mynb, 0), NPTS - 1);
    int nb_a = mynb;
    int nbm[4];
    #pragma unroll
    for (int r = 0; r < 4; ++r) nbm[r] = __shfl(mynb, quad * 4 + r);

    const float4 xq4 = *(const float4*)(xyzp + (size_t)p * 4);
    const float4 xn4 = *(const float4*)(xyzp + ((size_t)b * NPTS + nb_a) * 4);
    float rel0 = xq4.x - xn4.x, rel1 = xq4.y - xn4.y;
    float rel2 = xq4.z - xn4.z, rel3 = xq4.w - xn4.w;

    bf8_t pe1f[2];
    #pragma unroll
    for (int s = 0; s < 2; ++s) {
        int hb = s * 32 + quad * 8;
        float W0[8], W1[8], W2[8], W3[8], Bb[8];
        *(float4*)&W0[0] = *(const float4*)(Wp1 +       hb);
        *(float4*)&W0[4] = *(const float4*)(Wp1 +       hb + 4);
        *(float4*)&W1[0] = *(const float4*)(Wp1 +  64 + hb);
        *(float4*)&W1[4] = *(const float4*)(Wp1 +  64 + hb + 4);
        *(float4*)&W2[0] = *(const float4*)(Wp1 + 128 + hb);
        *(float4*)&W2[4] = *(const float4*)(Wp1 + 128 + hb + 4);
        *(float4*)&W3[0] = *(const float4*)(Wp1 + 192 + hb);
        *(float4*)&W3[4] = *(const float4*)(Wp1 + 192 + hb + 4);
        *(float4*)&Bb[0] = *(const float4*)(bp1 + hb);
        *(float4*)&Bb[4] = *(const float4*)(bp1 + hb + 4);
        #pragma unroll
        for (int j = 0; j < 8; ++j) {
            float a = Bb[j] + rel0 * W0[j] + rel1 * W1[j]
                            + rel2 * W2[j] + rel3 * W3[j];
            pe1f[s][j] = (short)f2b(fmaxf(a, 0.f));
        }
    }

    const bf8_t* BW = (const bf8_t*)fragw;
    f4_t pe2c[4];
    #pragma unroll
    for (int t = 0; t < 4; ++t) {
        f4_t acc = {0.f, 0.f, 0.f, 0.f};
        acc = MFMA16(pe1f[0], BW[0 * 512 + (0 * 4 + t) * 64 + lane], acc);
        acc = MFMA16(pe1f[1], BW[0 * 512 + (1 * 4 + t) * 64 + lane], acc);
        float bias = bp2[t * 16 + l15];
        #pragma unroll
        for (int r = 0; r < 4; ++r) acc[r] += bias;
        pe2c[t] = acc;
    }

    f4_t ainc[4], vpec[4];
    #pragma unroll
    for (int t = 0; t < 4; ++t) {
        float qv = qw[(size_t)p * HDIM + t * 16 + l15];
        #pragma unroll
        for (int r = 0; r < 4; ++r) {
            size_t nbo = ((size_t)b * NPTS + nbm[r]) * HDIM + t * 16 + l15;
            ainc[t][r] = qv - kw[nbo] + pe2c[t][r];
            vpec[t][r] = vw[nbo] + pe2c[t][r];
        }
    }

    #pragma unroll
    for (int t = 0; t < 4; ++t)
        #pragma unroll
        for (int r = 0; r < 4; ++r)
            bb[(quad * 4 + r) * 68 + t * 16 + l15] = ainc[t][r];
    asm volatile("s_waitcnt lgkmcnt(0)" ::: "memory");
    bf8_t af[2];
    #pragma unroll
    for (int s = 0; s < 2; ++s) {
        float tmp[8];
        *(float4*)&tmp[0] = *(const float4*)&bb[l15 * 68 + s * 32 + quad * 8];
        *(float4*)&tmp[4] = *(const float4*)&bb[l15 * 68 + s * 32 + quad * 8 + 4];
        #pragma unroll
        for (int j = 0; j < 8; ++j) af[s][j] = (short)f2b(tmp[j]);
    }

    f4_t t1c[4];
    #pragma unroll
    for (int t = 0; t < 4; ++t) {
        f4_t acc = {0.f, 0.f, 0.f, 0.f};
        acc = MFMA16(af[0], BW[1 * 512 + (0 * 4 + t) * 64 + lane], acc);
        acc = MFMA16(af[1], BW[1 * 512 + (1 * 4 + t) * 64 + lane], acc);
        float bias = bt1[t * 16 + l15];
        #pragma unroll
        for (int r = 0; r < 4; ++r) t1c[t][r] = fmaxf(acc[r] + bias, 0.f);
    }

    asm volatile("s_waitcnt lgkmcnt(0)" ::: "memory");
    #pragma unroll
    for (int t = 0; t < 4; ++t)
        #pragma unroll
        for (int r = 0; r < 4; ++r)
            bb[(quad * 4 + r) * 68 + t * 16 + l15] = t1c[t][r];
    asm volatile("s_waitcnt lgkmcnt(0)" ::: "memory");
    bf8_t tf[2];
    #pragma unroll
    for (int s = 0; s < 2; ++s) {
        float tmp[8];
        *(float4*)&tmp[0] = *(const float4*)&bb[l15 * 68 + s * 32 + quad * 8];
        *(float4*)&tmp[4] = *(const float4*)&bb[l15 * 68 + s * 32 + quad * 8 + 4];
        #pragma unroll
        for (int j = 0; j < 8; ++j) tf[s][j] = (short)f2b(tmp[j]);
    }

    f4_t lgc[4];
    #pragma unroll
    for (int t = 0; t < 4; ++t) {
        f4_t acc = {0.f, 0.f, 0.f, 0.f};
        acc = MFMA16(tf[0], BW[2 * 512 + (0 * 4 + t) * 64 + lane], acc);
        acc = MFMA16(tf[1], BW[2 * 512 + (1 * 4 + t) * 64 + lane], acc);
        float bias = bt2[t * 16 + l15];
        #pragma unroll
        for (int r = 0; r < 4; ++r) lgc[t][r] = (acc[r] + bias) * 0.125f;
    }

    float res[4];
    #pragma unroll
    for (int t = 0; t < 4; ++t) {
        float m0 = fmaxf(fmaxf(lgc[t][0], lgc[t][1]), fmaxf(lgc[t][2], lgc[t][3]));
        m0 = fmaxf(m0, __shfl_xor(m0, 16));
        m0 = fmaxf(m0, __shfl_xor(m0, 32));
        float e0 = fast_exp(lgc[t][0] - m0), e1 = fast_exp(lgc[t][1] - m0);
        float e2 = fast_exp(lgc[t][2] - m0), e3 = fast_exp(lgc[t][3] - m0);
        float sl = e0 + e1 + e2 + e3;
        float rl = e0 * vpec[t][0] + e1 * vpec[t][1]
                 + e2 * vpec[t][2] + e3 * vpec[t][3];
        sl += __shfl_xor(sl, 16); sl += __shfl_xor(sl, 32);
        rl += __shfl_xor(rl, 16); rl += __shfl_xor(rl, 32);
        res[t] = rl / sl;
    }

    float rh = (quad == 0) ? res[0] : (quad == 1) ? res[1]
             : (quad == 2) ? res[2] : res[3];
    float f = features[(size_t)p * HDIM + lane];
    float o = ba[lane];
    #pragma unroll 8
    for (int c = 0; c < 64; ++c) o += __shfl(rh, c) * Wa[c * 64 + lane];
    out[(size_t)p * HDIM + lane] = o + f;
}

// ---------------------------------------------------------------------------
extern "C" void kernel_launch(void* const* d_in, const int* in_sizes, int n_in,
                              void* d_out, int out_size, void* d_ws, size_t ws_size,
                              hipStream_t stream)
{
    (void)in_sizes; (void)n_in; (void)out_size; (void)ws_size;
    const float* xyzp     = (const float*)d_in[0];
    const float* features = (const float*)d_in[1];
    const float* Wk  = (const float*)d_in[2];
    const float* bk  = (const float*)d_in[3];
    const float* Wq  = (const float*)d_in[4];
    const float* Wks = (const float*)d_in[5];
    const float* Wv  = (const float*)d_in[6];
    const float* Wp1 = (const float*)d_in[7];
    const float* bp1 = (const float*)d_in[8];
    const float* Wp2 = (const float*)d_in[9];
    const float* bp2 = (const float*)d_in[10];
    const float* Wt1 = (const float*)d_in[11];
    const float* bt1 = (const float*)d_in[12];
    const float* Wt2 = (const float*)d_in[13];
    const float* bt2 = (const float*)d_in[14];
    const float* Wa  = (const float*)d_in[15];
    const float* ba  = (const float*)d_in[16];
    float* out = (float*)d_out;
    char* ws = (char*)d_ws;

    float* qw = (float*)(ws + OFF_QW);
    float* kw = (float*)(ws + OFF_KW);
    float* vw = (float*)(ws + OFF_VW);
    unsigned short* fragw = (unsigned short*)(ws + OFF_FRAG);
    int* knnIdx = (int*)(ws + OFF_KNN);

    fused_pre_kernel<<<PRE_BLOCKS + 3 * KNN_BLOCKS, 256, 0, stream>>>(
        xyzp, features, Wk, bk, Wq, Wks, Wv, Wp2, Wt1, Wt2,
        qw, kw, vw, fragw, knnIdx);
    LocalTransformer_80513456931527_kernel<<<(2 * NPTS) / 4, 256, 0, stream>>>(
        xyzp, features, Wp1, bp1, bp2, bt1, bt2, Wa, ba,
        qw, kw, vw, fragw, knnIdx, out);
}

// Round 11
// 327.851 us; speedup vs baseline: 1.1612x; 1.0240x over previous
//
#include <hip/hip_runtime.h>

#define NPTS 8192
#define HDIM 64
#define KNN 16
#define LOG2E 1.4426950408889634f

typedef __attribute__((ext_vector_type(8))) short bf8_t;   // 8 bf16
typedef __attribute__((ext_vector_type(4))) float f4_t;    // MFMA C/D
#define MFMA16(a, b, c) __builtin_amdgcn_mfma_f32_16x16x32_bf16(a, b, c, 0, 0, 0)

__device__ __forceinline__ float fast_exp(float x) {
    float y = x * LOG2E;
    float r;
    asm volatile("v_exp_f32 %0, %1\n\ts_nop 1" : "=v"(r) : "v"(y));
    return r;
}
__device__ __forceinline__ unsigned short f2b(float x) {   // f32 -> bf16 RNE
    unsigned v = __float_as_uint(x);
    return (unsigned short)((v + 0x7FFFu + ((v >> 16) & 1u)) >> 16);
}

// ws layout: qw 0..4MB, kw 4..8MB, vw 8..12MB, frag 12MB..+24KB, knnIdx +32KB..+1MB
#define OFF_QW   0u
#define OFF_KW   (4u << 20)
#define OFF_VW   (8u << 20)
#define OFF_FRAG (12u << 20)
#define OFF_KNN  ((12u << 20) + 32768u)     // ws >= 14.8 MB (established R12)

// ---------------------------------------------------------------------------
// fused_pre v2: prefrag + proj + knn in ONE dispatch.
// R24 post-mortem: fusion composed to ~max (243 vs 257 serial) but fused knn
// ran 36us slower than standalone (243 vs 207). Suspected cause: per-wave
// proj re-reads 64KB of W from L2 per wave (4096 waves = 262MB L2 traffic),
// contending with knn's latency-critical candidate loads. Fix: proj waves
// handle 4 points SEQUENTIALLY, loading each W column once per 4 points
// (register amortization, not LDS — LDS staging would couple block
// placement: 3x64KB > 160KB/CU stalls dispatch). W L2 traffic /4 -> ~65MB.
// Per-point FMA order unchanged -> bit-identical. proj = 1024 blocks; grid
// = 48 prefrag + triples (knn, knn, proj) = 3120 blocks total.
// knn path = R8/knn2 VERBATIM (best knn: 207us).
// ---------------------------------------------------------------------------
#define PRE_BLOCKS 48

__global__ __launch_bounds__(256) void fused_pre_kernel(
    const float* __restrict__ xyzp,
    const float* __restrict__ feat,
    const float* __restrict__ Wk, const float* __restrict__ bk,
    const float* __restrict__ Wq, const float* __restrict__ Wks,
    const float* __restrict__ Wv,
    const float* __restrict__ Wp2, const float* __restrict__ Wt1,
    const float* __restrict__ Wt2,
    float* __restrict__ qw, float* __restrict__ kw, float* __restrict__ vw,
    unsigned short* __restrict__ fragw,
    int* __restrict__ knnIdx)
{
    int bid = blockIdx.x;

    // ---------------- prefrag path (blocks 0..47), proven R11-R15 ----------
    if (bid < PRE_BLOCKS) {
        int i = bid * 256 + threadIdx.x;
        if (i >= 3 * 4096) return;
        int st = i >> 12, e = i & 4095;
        const float* W = (st == 0) ? Wp2 : (st == 1) ? Wt1 : Wt2;
        int k = e >> 6, n = e & 63;
        int s = k >> 5, quad = (k >> 3) & 3, j = k & 7;
        int t = n >> 4, l = quad * 16 + (n & 15);
        fragw[st * 4096 + (s * 4 + t) * 512 + l * 8 + j] = f2b(W[e]);
        return;
    }

    int j3 = bid - PRE_BLOCKS;
    int group = j3 / 3, pos = j3 - group * 3;     // groups 0..1023
    int w = threadIdx.x >> 6, lane = threadIdx.x & 63;

    // ---------------- proj path: 4 points/wave, W columns amortized --------
    if (pos == 2) {
        int p0 = group * 16 + w * 4;               // 16 points per block
        float f0 = feat[(size_t)(p0 + 0) * HDIM + lane];
        float f1 = feat[(size_t)(p0 + 1) * HDIM + lane];
        float f2 = feat[(size_t)(p0 + 2) * HDIM + lane];
        float f3 = feat[(size_t)(p0 + 3) * HDIM + lane];
        float bkl = bk[lane];
        float x0 = bkl, x1 = bkl, x2 = bkl, x3 = bkl;
        #pragma unroll 8
        for (int c = 0; c < 64; ++c) {
            float col = Wk[c * 64 + lane];
            x0 += __shfl(f0, c) * col;
            x1 += __shfl(f1, c) * col;
            x2 += __shfl(f2, c) * col;
            x3 += __shfl(f3, c) * col;
        }
        float q0 = 0.f, q1 = 0.f, q2 = 0.f, q3 = 0.f;
        float k0 = 0.f, k1 = 0.f, k2 = 0.f, k3 = 0.f;
        float v0 = 0.f, v1 = 0.f, v2 = 0.f, v3 = 0.f;
        #pragma unroll 4
        for (int c = 0; c < 64; ++c) {
            float cq = Wq[c * 64 + lane];
            float ck = Wks[c * 64 + lane];
            float cv = Wv[c * 64 + lane];
            float a0 = __shfl(x0, c), a1 = __shfl(x1, c);
            float a2 = __shfl(x2, c), a3 = __shfl(x3, c);
            q0 += a0 * cq; k0 += a0 * ck; v0 += a0 * cv;
            q1 += a1 * cq; k1 += a1 * ck; v1 += a1 * cv;
            q2 += a2 * cq; k2 += a2 * ck; v2 += a2 * cv;
            q3 += a3 * cq; k3 += a3 * ck; v3 += a3 * cv;
        }
        qw[(size_t)(p0 + 0) * HDIM + lane] = q0;
        qw[(size_t)(p0 + 1) * HDIM + lane] = q1;
        qw[(size_t)(p0 + 2) * HDIM + lane] = q2;
        qw[(size_t)(p0 + 3) * HDIM + lane] = q3;
        kw[(size_t)(p0 + 0) * HDIM + lane] = k0;
        kw[(size_t)(p0 + 1) * HDIM + lane] = k1;
        kw[(size_t)(p0 + 2) * HDIM + lane] = k2;
        kw[(size_t)(p0 + 3) * HDIM + lane] = k3;
        vw[(size_t)(p0 + 0) * HDIM + lane] = v0;
        vw[(size_t)(p0 + 1) * HDIM + lane] = v1;
        vw[(size_t)(p0 + 2) * HDIM + lane] = v2;
        vw[(size_t)(p0 + 3) * HDIM + lane] = v3;
        return;
    }

    // ---------------- knn path (R8/knn2 body VERBATIM: best knn, 207us) ----
    int wid = (group * 2 + pos) * 4 + w;  // wave id 0..8191
    int pbase = wid * 2;                 // 2 consecutive points, same batch
    int b = pbase >> 13;
    int nbase = pbase & (NPTS - 1);
    const float4* xb4 = (const float4*)xyzp + (size_t)b * NPTS;

    float qx[2], qy[2], qz[2], qs[2];
    #pragma unroll
    for (int qi = 0; qi < 2; ++qi) {
        float4 s = xb4[nbase + qi];
        qx[qi] = s.x; qy[qi] = s.y; qz[qi] = s.z;
        qs[qi] = s.x * s.x + s.y * s.y + s.z * s.z;
    }

    float dh[2][4]; int ih[2][4];
    #pragma unroll
    for (int qi = 0; qi < 2; ++qi)
        #pragma unroll
        for (int j = 0; j < 4; ++j) { dh[qi][j] = 3.4e38f; ih[qi][j] = 0x7fffffff; }

    float tau[2];
    tau[0] = 3.4e38f; tau[1] = 3.4e38f;

    #pragma unroll 1
    for (int t = 0; t < NPTS / 256; ++t) {          // 32 iters x 256 cands
        float4 c[4];
        #pragma unroll
        for (int u = 0; u < 4; ++u)
            c[u] = xb4[(t * 4 + u) * 64 + lane];
        #pragma unroll
        for (int u = 0; u < 4; ++u) {
            int m = (t * 4 + u) * 64 + lane;
            float cs = c[u].x * c[u].x + c[u].y * c[u].y + c[u].z * c[u].z;
            #pragma unroll
            for (int qi = 0; qi < 2; ++qi) {
                float d = qs[qi] + cs
                        - 2.0f * (qx[qi] * c[u].x + qy[qi] * c[u].y + qz[qi] * c[u].z);
                if (__any(d <= tau[qi])) {
                    // branchless sorted insert (strict <, ties keep lower idx)
                    bool c3 = d < dh[qi][3];
                    bool c2 = d < dh[qi][2];
                    bool c1 = d < dh[qi][1];
                    bool c0 = d < dh[qi][0];
                    dh[qi][3] = c2 ? dh[qi][2] : (c3 ? d : dh[qi][3]);
                    ih[qi][3] = c2 ? ih[qi][2] : (c3 ? m : ih[qi][3]);
                    dh[qi][2] = c1 ? dh[qi][1] : (c2 ? d : dh[qi][2]);
                    ih[qi][2] = c1 ? ih[qi][1] : (c2 ? m : ih[qi][2]);
                    dh[qi][1] = c0 ? dh[qi][0] : (c1 ? d : dh[qi][1]);
                    ih[qi][1] = c0 ? ih[qi][0] : (c1 ? m : ih[qi][1]);
                    dh[qi][0] = c0 ? d : dh[qi][0];
                    ih[qi][0] = c0 ? m : ih[qi][0];
                }
            }
        }
        if (t & 1) {
            // tau = max over 4 groups-of-16 of (min over group of dh[3]):
            // valid upper bound on final global 16th-best (proven R18)
            #pragma unroll
            for (int qi = 0; qi < 2; ++qi) {
                float t4 = dh[qi][3];
                t4 = fminf(t4, __shfl_xor(t4, 1));
                t4 = fminf(t4, __shfl_xor(t4, 2));
                t4 = fminf(t4, __shfl_xor(t4, 4));
                t4 = fminf(t4, __shfl_xor(t4, 8));
                t4 = fmaxf(t4, __shfl_xor(t4, 16));
                t4 = fmaxf(t4, __shfl_xor(t4, 32));
                tau[qi] = t4;
            }
        }
    }

    // per-qi exact top-16 extraction + full-range repair (proven R18 code,
    // qi fully unrolled: rule #20).
    #pragma unroll
    for (int qi = 0; qi < 2; ++qi) {
        int mynb = 0, head = 0;
        #pragma unroll 1
        for (int r = 0; r < KNN; ++r) {
            float d = dh[qi][0]; int i = ih[qi][0];
            #pragma unroll
            for (int s = 1; s < 64; s <<= 1) {
                float d2 = __shfl_xor(d, s); int i2 = __shfl_xor(i, s);
                if (d2 < d || (d2 == d && i2 < i)) { d = d2; i = i2; }
            }
            if (lane == r) mynb = i;
            if (ih[qi][0] == i) {
                dh[qi][0] = dh[qi][1]; ih[qi][0] = ih[qi][1];
                dh[qi][1] = dh[qi][2]; ih[qi][1] = ih[qi][2];
                dh[qi][2] = dh[qi][3]; ih[qi][2] = ih[qi][3];
                dh[qi][3] = 3.4e38f; ih[qi][3] = 0x7fffffff;
                ++head;
            }
        }
        // exact repair (proven R13-R15): ~0.7%/query
        if (__any(head >= 4)) {
            float eh[16]; int ei[16];
            #pragma unroll
            for (int j = 0; j < 16; ++j) { eh[j] = 3.4e38f; ei[j] = 0x7fffffff; }
            for (int t = 0; t < NPTS / 64; ++t) {
                int m = t * 64 + lane;
                float4 c4 = xb4[m];
                float cs = c4.x * c4.x + c4.y * c4.y + c4.z * c4.z;
                float d = qs[qi] + cs
                        - 2.0f * (qx[qi] * c4.x + qy[qi] * c4.y + qz[qi] * c4.z);
                if (d < eh[15]) {
                    eh[15] = d; ei[15] = m;
                    #pragma unroll
                    for (int j = 15; j >= 1; --j)
                        if (eh[j] < eh[j - 1]) {
                            float td = eh[j]; eh[j] = eh[j - 1]; eh[j - 1] = td;
                            int ti = ei[j]; ei[j] = ei[j - 1]; ei[j - 1] = ti;
                        }
                }
            }
            #pragma unroll 1
            for (int r = 0; r < KNN; ++r) {
                float d = eh[0]; int i = ei[0];
                #pragma unroll
                for (int s = 1; s < 64; s <<= 1) {
                    float d2 = __shfl_xor(d, s); int i2 = __shfl_xor(i, s);
                    if (d2 < d || (d2 == d && i2 < i)) { d = d2; i = i2; }
                }
                if (lane == r) mynb = i;
                if (ei[0] == i) {
                    #pragma unroll
                    for (int j = 0; j < 15; ++j) { eh[j] = eh[j + 1]; ei[j] = ei[j + 1]; }
                    eh[15] = 3.4e38f; ei[15] = 0x7fffffff;
                }
            }
        }
        mynb = min(max(mynb, 0), NPTS - 1);
        if (lane < KNN) knnIdx[(size_t)(pbase + qi) * KNN + lane] = mynb;
    }
}

// ---------------------------------------------------------------------------
// main: MFMA per-neighbor MLPs consuming knnIdx (proven verbatim R12/R14/R15).
// ---------------------------------------------------------------------------
__global__ __launch_bounds__(256) void LocalTransformer_80513456931527_kernel(
    const float* __restrict__ xyzp, const float* __restrict__ features,
    const float* __restrict__ Wp1,  const float* __restrict__ bp1,
    const float* __restrict__ bp2,  const float* __restrict__ bt1,
    const float* __restrict__ bt2,
    const float* __restrict__ Wa,   const float* __restrict__ ba,
    const float* __restrict__ qw, const float* __restrict__ kw,
    const float* __restrict__ vw,
    const unsigned short* __restrict__ fragw,
    const int* __restrict__ knnIdx,
    float* __restrict__ out)
{
    __shared__ __align__(16) float sBounce[4][16 * 68 + 4];

    int tid = threadIdx.x, w = tid >> 6, lane = tid & 63;
    int p = blockIdx.x * 4 + w;
    int b = p >> 13;
    float* bb = sBounce[w];

    int quad = lane >> 4, l15 = lane & 15;
    int mynb = knnIdx[(size_t)p * KNN + l15];
    mynb = min(max(mynb, 0), NPTS - 1);
    int nb_a = mynb;
    int nbm[4];
    #pragma unroll
    for (int r = 0; r < 4; ++r) nbm[r] = __shfl(mynb, quad * 4 + r);

    const float4 xq4 = *(const float4*)(xyzp + (size_t)p * 4);
    const float4 xn4 = *(const float4*)(xyzp + ((size_t)b * NPTS + nb_a) * 4);
    float rel0 = xq4.x - xn4.x, rel1 = xq4.y - xn4.y;
    float rel2 = xq4.z - xn4.z, rel3 = xq4.w - xn4.w;

    bf8_t pe1f[2];
    #pragma unroll
    for (int s = 0; s < 2; ++s) {
        int hb = s * 32 + quad * 8;
        float W0[8], W1[8], W2[8], W3[8], Bb[8];
        *(float4*)&W0[0] = *(const float4*)(Wp1 +       hb);
        *(float4*)&W0[4] = *(const float4*)(Wp1 +       hb + 4);
        *(float4*)&W1[0] = *(const float4*)(Wp1 +  64 + hb);
        *(float4*)&W1[4] = *(const float4*)(Wp1 +  64 + hb + 4);
        *(float4*)&W2[0] = *(const float4*)(Wp1 + 128 + hb);
        *(float4*)&W2[4] = *(const float4*)(Wp1 + 128 + hb + 4);
        *(float4*)&W3[0] = *(const float4*)(Wp1 + 192 + hb);
        *(float4*)&W3[4] = *(const float4*)(Wp1 + 192 + hb + 4);
        *(float4*)&Bb[0] = *(const float4*)(bp1 + hb);
        *(float4*)&Bb[4] = *(const float4*)(bp1 + hb + 4);
        #pragma unroll
        for (int j = 0; j < 8; ++j) {
            float a = Bb[j] + rel0 * W0[j] + rel1 * W1[j]
                            + rel2 * W2[j] + rel3 * W3[j];
            pe1f[s][j] = (short)f2b(fmaxf(a, 0.f));
        }
    }

    const bf8_t* BW = (const bf8_t*)fragw;
    f4_t pe2c[4];
    #pragma unroll
    for (int t = 0; t < 4; ++t) {
        f4_t acc = {0.f, 0.f, 0.f, 0.f};
        acc = MFMA16(pe1f[0], BW[0 * 512 + (0 * 4 + t) * 64 + lane], acc);
        acc = MFMA16(pe1f[1], BW[0 * 512 + (1 * 4 + t) * 64 + lane], acc);
        float bias = bp2[t * 16 + l15];
        #pragma unroll
        for (int r = 0; r < 4; ++r) acc[r] += bias;
        pe2c[t] = acc;
    }

    f4_t ainc[4], vpec[4];
    #pragma unroll
    for (int t = 0; t < 4; ++t) {
        float qv = qw[(size_t)p * HDIM + t * 16 + l15];
        #pragma unroll
        for (int r = 0; r < 4; ++r) {
            size_t nbo = ((size_t)b * NPTS + nbm[r]) * HDIM + t * 16 + l15;
            ainc[t][r] = qv - kw[nbo] + pe2c[t][r];
            vpec[t][r] = vw[nbo] + pe2c[t][r];
        }
    }

    #pragma unroll
    for (int t = 0; t < 4; ++t)
        #pragma unroll
        for (int r = 0; r < 4; ++r)
            bb[(quad * 4 + r) * 68 + t * 16 + l15] = ainc[t][r];
    asm volatile("s_waitcnt lgkmcnt(0)" ::: "memory");
    bf8_t af[2];
    #pragma unroll
    for (int s = 0; s < 2; ++s) {
        float tmp[8];
        *(float4*)&tmp[0] = *(const float4*)&bb[l15 * 68 + s * 32 + quad * 8];
        *(float4*)&tmp[4] = *(const float4*)&bb[l15 * 68 + s * 32 + quad * 8 + 4];
        #pragma unroll
        for (int j = 0; j < 8; ++j) af[s][j] = (short)f2b(tmp[j]);
    }

    f4_t t1c[4];
    #pragma unroll
    for (int t = 0; t < 4; ++t) {
        f4_t acc = {0.f, 0.f, 0.f, 0.f};
        acc = MFMA16(af[0], BW[1 * 512 + (0 * 4 + t) * 64 + lane], acc);
        acc = MFMA16(af[1], BW[1 * 512 + (1 * 4 + t) * 64 + lane], acc);
        float bias = bt1[t * 16 + l15];
        #pragma unroll
        for (int r = 0; r < 4; ++r) t1c[t][r] = fmaxf(acc[r] + bias, 0.f);
    }

    asm volatile("s_waitcnt lgkmcnt(0)" ::: "memory");
    #pragma unroll
    for (int t = 0; t < 4; ++t)
        #pragma unroll
        for (int r = 0; r < 4; ++r)
            bb[(quad * 4 + r) * 68 + t * 16 + l15] = t1c[t][r];
    asm volatile("s_waitcnt lgkmcnt(0)" ::: "memory");
    bf8_t tf[2];
    #pragma unroll
    for (int s = 0; s < 2; ++s) {
        float tmp[8];
        *(float4*)&tmp[0] = *(const float4*)&bb[l15 * 68 + s * 32 + quad * 8];
        *(float4*)&tmp[4] = *(const float4*)&bb[l15 * 68 + s * 32 + quad * 8 + 4];
        #pragma unroll
        for (int j = 0; j < 8; ++j) tf[s][j] = (short)f2b(tmp[j]);
    }

    f4_t lgc[4];
    #pragma unroll
    for (int t = 0; t < 4; ++t) {
        f4_t acc = {0.f, 0.f, 0.f, 0.f};
        acc = MFMA16(tf[0], BW[2 * 512 + (0 * 4 + t) * 64 + lane], acc);
        acc = MFMA16(tf[1], BW[2 * 512 + (1 * 4 + t) * 64 + lane], acc);
        float bias = bt2[t * 16 + l15];
        #pragma unroll
        for (int r = 0; r < 4; ++r) lgc[t][r] = (acc[r] + bias) * 0.125f;
    }

    float res[4];
    #pragma unroll
    for (int t = 0; t < 4; ++t) {
        float m0 = fmaxf(fmaxf(lgc[t][0], lgc[t][1]), fmaxf(lgc[t][2], lgc[t][3]));
        m0 = fmaxf(m0, __shfl_xor(m0, 16));
        m0 = fmaxf(m0, __shfl_xor(m0, 32));
        float e0 = fast_exp(lgc[t][0] - m0), e1 = fast_exp(lgc[t][1] - m0);
        float e2 = fast_exp(lgc[t][2] - m0), e3 = fast_exp(lgc[t][3] - m0);
        float sl = e0 + e1 + e2 + e3;
        float rl = e0 * vpec[t][0] + e1 * vpec[t][1]
                 + e2 * vpec[t][2] + e3 * vpec[t][3];
        sl += __shfl_xor(sl, 16); sl += __shfl_xor(sl, 32);
        rl += __shfl_xor(rl, 16); rl += __shfl_xor(rl, 32);
        res[t] = rl / sl;
    }

    float rh = (quad == 0) ? res[0] : (quad == 1) ? res[1]
             : (quad == 2) ? res[2] : res[3];
    float f = features[(size_t)p * HDIM + lane];
    float o = ba[lane];
    #pragma unroll 8
    for (int c = 0; c < 64; ++c) o += __shfl(rh, c) * Wa[c * 64 + lane];
    out[(size_t)p * HDIM + lane] = o + f;
}

// ---------------------------------------------------------------------------
extern "C" void kernel_launch(void* const* d_in, const int* in_sizes, int n_in,
                              void* d_out, int out_size, void* d_ws, size_t ws_size,
                              hipStream_t stream)
{
    (void)in_sizes; (void)n_in; (void)out_size; (void)ws_size;
    const float* xyzp     = (const float*)d_in[0];
    const float* features = (const float*)d_in[1];
    const float* Wk  = (const float*)d_in[2];
    const float* bk  = (const float*)d_in[3];
    const float* Wq  = (const float*)d_in[4];
    const float* Wks = (const float*)d_in[5];
    const float* Wv  = (const float*)d_in[6];
    const float* Wp1 = (const float*)d_in[7];
    const float* bp1 = (const float*)d_in[8];
    const float* Wp2 = (const float*)d_in[9];
    const float* bp2 = (const float*)d_in[10];
    const float* Wt1 = (const float*)d_in[11];
    const float* bt1 = (const float*)d_in[12];
    const float* Wt2 = (const float*)d_in[13];
    const float* bt2 = (const float*)d_in[14];
    const float* Wa  = (const float*)d_in[15];
    const float* ba  = (const float*)d_in[16];
    float* out = (float*)d_out;
    char* ws = (char*)d_ws;

    float* qw = (float*)(ws + OFF_QW);
    float* kw = (float*)(ws + OFF_KW);
    float* vw = (float*)(ws + OFF_VW);
    unsigned short* fragw = (unsigned short*)(ws + OFF_FRAG);
    int* knnIdx = (int*)(ws + OFF_KNN);

    fused_pre_kernel<<<PRE_BLOCKS + 3 * 1024, 256, 0, stream>>>(
        xyzp, features, Wk, bk, Wq, Wks, Wv, Wp2, Wt1, Wt2,
        qw, kw, vw, fragw, knnIdx);
    LocalTransformer_80513456931527_kernel<<<(2 * NPTS) / 4, 256, 0, stream>>>(
        xyzp, features, Wp1, bp1, bp2, bt1, bt2, Wa, ba,
        qw, kw, vw, fragw, knnIdx, out);
}